// Round 11
// baseline (318.423 us; speedup 1.0000x reference)
//
#include <hip/hip_runtime.h>

#define DEV __device__ __forceinline__

typedef __attribute__((ext_vector_type(8))) short short8;
typedef __attribute__((ext_vector_type(4))) short short4v;
typedef __attribute__((ext_vector_type(4))) float f32x4;

// ---------- bf16 helpers ----------
DEV float bf2f(unsigned short u) { return __uint_as_float(((unsigned int)u) << 16); }
DEV unsigned short f2bf(float f) {
    unsigned int u = __float_as_uint(f);
    u += 0x7FFFu + ((u >> 16) & 1u);   // RNE
    return (unsigned short)(u >> 16);
}

DEV float elu1(float v) { return v > 0.0f ? v + 1.0f : __expf(v); }

// ---------- async global->LDS, 16B per lane ----------
DEV void gload_lds16(const void* g, void* l) {
    __builtin_amdgcn_global_load_lds(
        (__attribute__((address_space(1))) unsigned int*)(g),
        (__attribute__((address_space(3))) unsigned int*)(l),
        16, 0, 0);
}

// Problem constants: B=4, NQ=NC=4096, D=1024, H=16, HD=64
#define NROW 16384
#define DDIM 1024

// =====================================================================
// LayerNorm (rows 0..2*NROW-1) + weight-convert (blocks >= 2*NROW).
// =====================================================================
__global__ __launch_bounds__(256) void ln_kernel(
    const float* __restrict__ query, const float* __restrict__ context,
    const float* __restrict__ lnq_g, const float* __restrict__ lnq_b,
    const float* __restrict__ lnk_g, const float* __restrict__ lnk_b,
    unsigned short* __restrict__ qln, unsigned short* __restrict__ cln,
    const float* __restrict__ q_w, const float* __restrict__ k_w,
    const float* __restrict__ v_w, const float* __restrict__ o_w,
    unsigned short* __restrict__ wout)
{
    const int tid = threadIdx.x;
    if (blockIdx.x >= 2 * NROW) {
        // conv_w branch: 4096 blocks, 4 f32->bf16 each thread
        const int i = (blockIdx.x - 2 * NROW) * 256 + tid;
        const int mat = i >> 18;
        const int idx = (i & 262143) * 4;
        const float* src = mat == 0 ? q_w : mat == 1 ? k_w : mat == 2 ? v_w : o_w;
        f32x4 v = *(const f32x4*)(src + idx);
        short4v o;
#pragma unroll
        for (int j = 0; j < 4; ++j) o[j] = (short)f2bf(v[j]);
        *(short4v*)(wout + (size_t)mat * 1048576 + idx) = o;
        return;
    }

    const int row = blockIdx.x;
    const bool isq = row < NROW;
    const int r = isq ? row : row - NROW;
    const float* src = (isq ? query : context) + (size_t)r * DDIM;
    const float* g   = isq ? lnq_g : lnk_g;
    const float* bb  = isq ? lnq_b : lnk_b;
    unsigned short* dst = (isq ? qln : cln) + (size_t)r * DDIM;

    f32x4 x = *(const f32x4*)(src + tid * 4);
    float s  = x[0] + x[1] + x[2] + x[3];
    float sq = x[0]*x[0] + x[1]*x[1] + x[2]*x[2] + x[3]*x[3];
#pragma unroll
    for (int off = 32; off; off >>= 1) {
        s  += __shfl_xor(s, off);
        sq += __shfl_xor(sq, off);
    }
    __shared__ float red[8];
    const int lane = tid & 63, w = tid >> 6;
    if (lane == 0) { red[w] = s; red[4 + w] = sq; }
    __syncthreads();
    s  = red[0] + red[1] + red[2] + red[3];
    sq = red[4] + red[5] + red[6] + red[7];
    const float mu  = s * (1.0f / DDIM);
    const float var = sq * (1.0f / DDIM) - mu * mu;
    const float rstd = rsqrtf(var + 1e-5f);

    f32x4 gv = *(const f32x4*)(g + tid * 4);
    f32x4 bv = *(const f32x4*)(bb + tid * 4);
    short4v o;
#pragma unroll
    for (int j = 0; j < 4; ++j)
        o[j] = (short)f2bf((x[j] - mu) * rstd * gv[j] + bv[j]);
    *(short4v*)(dst + tid * 4) = o;
}

// =====================================================================
// 128x128-tile GEMM core (round-9 verified: 0 conflicts, occ 36%, 736 TF)
// =====================================================================
template <typename EPI>
DEV void gemm128(unsigned short* __restrict__ sA,
                 unsigned short* __restrict__ sB,
                 const unsigned short* __restrict__ Ap,
                 const unsigned short* __restrict__ Bp,
                 int m0, int n0, EPI epi)
{
    const int tid = threadIdx.x;
    const int lane = tid & 63, w = tid >> 6;
    const int wr = w >> 1, wc = w & 1;
    const int lr = lane & 15, lg = lane >> 4;

    const int srow = tid >> 3;
    const int cswz = (tid & 7) ^ (srow & 7);
    const unsigned short* gA0 = Ap + (size_t)(m0 + srow) * 1024 + cswz * 8;
    const unsigned short* gB0 = Bp + (size_t)(n0 + srow) * 1024 + cswz * 8;
    unsigned short* dA = sA + tid * 8;
    unsigned short* dB = sB + tid * 8;

    const int sw0 = ((0 + lg) ^ (lr & 7)) * 8;
    const int sw1 = ((4 + lg) ^ (lr & 7)) * 8;

    f32x4 acc[4][4];
#pragma unroll
    for (int i = 0; i < 4; ++i)
#pragma unroll
        for (int j = 0; j < 4; ++j)
#pragma unroll
            for (int e = 0; e < 4; ++e) acc[i][j][e] = 0.0f;

#define STG8(T)                                                               \
    {                                                                         \
        const int ko = (T) * 64;                                              \
        _Pragma("unroll")                                                     \
        for (int j = 0; j < 4; ++j) {                                         \
            gload_lds16(gA0 + ko + (size_t)j * 32768, dA + j * 2048);         \
            gload_lds16(gB0 + ko + (size_t)j * 32768, dB + j * 2048);         \
        }                                                                     \
    }

    STG8(0);
    for (int t = 0; t < 16; ++t) {
        asm volatile("s_waitcnt vmcnt(0)" ::: "memory");
        __builtin_amdgcn_s_barrier();

        short8 af[4], bf[4];
#pragma unroll
        for (int mt = 0; mt < 4; ++mt)
            af[mt] = *(const short8*)&sA[(wr * 64 + mt * 16 + lr) * 64 + sw0];
#pragma unroll
        for (int nt = 0; nt < 4; ++nt)
            bf[nt] = *(const short8*)&sB[(wc * 64 + nt * 16 + lr) * 64 + sw0];
        __builtin_amdgcn_s_setprio(1);
#pragma unroll
        for (int mt = 0; mt < 4; ++mt)
#pragma unroll
            for (int nt = 0; nt < 4; ++nt)
                acc[mt][nt] = __builtin_amdgcn_mfma_f32_16x16x32_bf16(
                    af[mt], bf[nt], acc[mt][nt], 0, 0, 0);
        __builtin_amdgcn_s_setprio(0);

#pragma unroll
        for (int mt = 0; mt < 4; ++mt)
            af[mt] = *(const short8*)&sA[(wr * 64 + mt * 16 + lr) * 64 + sw1];
#pragma unroll
        for (int nt = 0; nt < 4; ++nt)
            bf[nt] = *(const short8*)&sB[(wc * 64 + nt * 16 + lr) * 64 + sw1];
        asm volatile("s_waitcnt lgkmcnt(0)" ::: "memory");
        __builtin_amdgcn_s_barrier();
        if (t < 15) STG8(t + 1);
        __builtin_amdgcn_s_setprio(1);
#pragma unroll
        for (int mt = 0; mt < 4; ++mt)
#pragma unroll
            for (int nt = 0; nt < 4; ++nt)
                acc[mt][nt] = __builtin_amdgcn_mfma_f32_16x16x32_bf16(
                    af[mt], bf[nt], acc[mt][nt], 0, 0, 0);
        __builtin_amdgcn_s_setprio(0);
    }
#undef STG8

#pragma unroll
    for (int mt = 0; mt < 4; ++mt)
#pragma unroll
        for (int nt = 0; nt < 4; ++nt) {
            const int col = n0 + wc * 64 + nt * 16 + lr;
#pragma unroll
            for (int i = 0; i < 4; ++i) {
                const int row = m0 + wr * 64 + mt * 16 + lg * 4 + i;
                epi(row, col, acc[mt][nt][i]);
            }
        }
}

// ---- merged projections: Q-proj (1024 tiles) + KV-proj (2048 tiles) ----
__global__ __launch_bounds__(256, 4) void gemm_qkv(
    const unsigned short* __restrict__ QLN, const unsigned short* __restrict__ WQ,
    const unsigned short* __restrict__ CLN, const unsigned short* __restrict__ WKV,
    unsigned short* __restrict__ Qm, unsigned short* __restrict__ KVT,
    const float* __restrict__ q_b, const float* __restrict__ k_b,
    const float* __restrict__ v_b)
{
    __shared__ __attribute__((aligned(16))) unsigned short sA[128 * 64];
    __shared__ __attribute__((aligned(16))) unsigned short sB[128 * 64];

    const int bid = blockIdx.x;                  // 3072 blocks
    const int l = (bid & 7) * 384 + (bid >> 3);  // XCD-chunked

    if (l < 1024) {
        const int m0 = (l >> 3) * 128, n0 = (l & 7) * 128;
        gemm128(sA, sB, QLN, WQ, m0, n0,
            [&](int row, int col, float v) {
                v = elu1(v + q_b[col]);
                Qm[(size_t)row * 1024 + col] = f2bf(v);
            });
    } else {
        const int r = l - 1024;                  // 0..2047
        const int m0 = (r & 15) * 128, n0 = (r >> 4) * 128;
        gemm128(sA, sB, WKV, CLN, m0, n0,
            [&](int row, int col, float v) {
                if (row < 1024) v = elu1(v + k_b[row]);
                else            v = v + v_b[row - 1024];
                KVT[(size_t)row * NROW + col] = f2bf(v);
            });
    }
}

// =====================================================================
// O-projection: round-5 deep-pipelined 256x256/BK=64/8-wave kernel.
// =====================================================================
__global__ __launch_bounds__(512, 2) void gemm_out256(
    const unsigned short* __restrict__ A, const unsigned short* __restrict__ Bm,
    float* __restrict__ Cout, const float* __restrict__ bias,
    const float* __restrict__ resid)
{
    __shared__ __attribute__((aligned(16))) unsigned short smem[65536];
    unsigned short* sAb = smem;           // 2 x 16384
    unsigned short* sBb = smem + 32768;   // 2 x 16384

    const int bid = blockIdx.x;           // 256 blocks
    const int l = (bid & 7) * 32 + (bid >> 3);
    const int m0 = (l >> 2) * 256, n0 = (l & 3) * 256;

    const int tid = threadIdx.x;
    const int lane = tid & 63, w = tid >> 6;
    const int wr = w >> 2, wc = w & 3;          // 2 x 4 wave grid
    const int lr = lane & 15, lg = lane >> 4;

    const int srow = tid >> 3;
    const int cswz = (tid & 7) ^ (srow & 7);
    const unsigned short* gA0 = A  + (size_t)(m0 + srow) * 1024 + cswz * 8;
    const unsigned short* gB0 = Bm + (size_t)(n0 + srow) * 1024 + cswz * 8;

    const int sw0 = ((0 + lg) ^ (lr & 7)) * 8;
    const int sw1 = ((4 + lg) ^ (lr & 7)) * 8;

    f32x4 acc[8][4];
#pragma unroll
    for (int i = 0; i < 8; ++i)
#pragma unroll
        for (int j = 0; j < 4; ++j)
#pragma unroll
            for (int e = 0; e < 4; ++e) acc[i][j][e] = 0.0f;

#define STG(GP, SP, T)                                                        \
    {                                                                         \
        const unsigned short* g = (GP) + (T) * 64;                            \
        unsigned short* d = (SP) + ((T) & 1) * 16384 + tid * 8;               \
        _Pragma("unroll")                                                     \
        for (int L = 0; L < 4; ++L)                                           \
            gload_lds16(g + (size_t)L * 65536, d + L * 4096);                 \
    }

    STG(gB0, sBb, 0); STG(gA0, sAb, 0); STG(gB0, sBb, 1); STG(gA0, sAb, 1);
    asm volatile("s_waitcnt vmcnt(8)" ::: "memory");
    __builtin_amdgcn_s_barrier();

    short8 bvl[2][2];
#pragma unroll
    for (int nt = 0; nt < 2; ++nt) {
        const int rb = (wc * 64 + nt * 16 + lr) * 64;
        bvl[nt][0] = *(const short8*)&sBb[rb + sw0];
        bvl[nt][1] = *(const short8*)&sBb[rb + sw1];
    }

    for (int t = 0; t < 16; ++t) {
        const unsigned short* bA = sAb + (t & 1) * 16384;
        const unsigned short* bB = sBb + (t & 1) * 16384;
        const unsigned short* bBn = sBb + ((t + 1) & 1) * 16384;
        short8 afl[4][2], afh[4][2], bvh[2][2], bvln[2][2];

        // ---- P0 ----
#pragma unroll
        for (int mt = 0; mt < 4; ++mt) {
            const int ra = (wr * 128 + mt * 16 + lr) * 64;
            afl[mt][0] = *(const short8*)&bA[ra + sw0];
            afl[mt][1] = *(const short8*)&bA[ra + sw1];
        }
#pragma unroll
        for (int mt = 0; mt < 4; ++mt) {
            const int ra = (wr * 128 + (mt + 4) * 16 + lr) * 64;
            afh[mt][0] = *(const short8*)&bA[ra + sw0];
            afh[mt][1] = *(const short8*)&bA[ra + sw1];
        }
        asm volatile("s_waitcnt lgkmcnt(8)" ::: "memory");
        __builtin_amdgcn_s_setprio(1);
#pragma unroll
        for (int kk = 0; kk < 2; ++kk)
#pragma unroll
            for (int mt = 0; mt < 4; ++mt)
#pragma unroll
                for (int nt = 0; nt < 2; ++nt)
                    acc[mt][nt] = __builtin_amdgcn_mfma_f32_16x16x32_bf16(
                        afl[mt][kk], bvl[nt][kk], acc[mt][nt], 0, 0, 0);
        __builtin_amdgcn_s_setprio(0);
        __builtin_amdgcn_s_barrier();

        // ---- P1 ----
#pragma unroll
        for (int nt = 0; nt < 2; ++nt) {
            const int rb = (wc * 64 + (nt + 2) * 16 + lr) * 64;
            bvh[nt][0] = *(const short8*)&bB[rb + sw0];
            bvh[nt][1] = *(const short8*)&bB[rb + sw1];
        }
        asm volatile("s_waitcnt lgkmcnt(4)" ::: "memory");
        __builtin_amdgcn_s_setprio(1);
#pragma unroll
        for (int kk = 0; kk < 2; ++kk)
#pragma unroll
            for (int mt = 0; mt < 4; ++mt)
#pragma unroll
                for (int nt = 0; nt < 2; ++nt)
                    acc[mt + 4][nt] = __builtin_amdgcn_mfma_f32_16x16x32_bf16(
                        afh[mt][kk], bvl[nt][kk], acc[mt + 4][nt], 0, 0, 0);
        __builtin_amdgcn_s_setprio(0);
        asm volatile("s_waitcnt vmcnt(0)" ::: "memory");
        __builtin_amdgcn_s_barrier();

        // ---- P2 ----
        if (t < 15) {
#pragma unroll
            for (int nt = 0; nt < 2; ++nt) {
                const int rb = (wc * 64 + nt * 16 + lr) * 64;
                bvln[nt][0] = *(const short8*)&bBn[rb + sw0];
                bvln[nt][1] = *(const short8*)&bBn[rb + sw1];
            }
        }
        if (t + 2 < 16) STG(gA0, sAb, t + 2);
        if (t < 15) asm volatile("s_waitcnt lgkmcnt(4)" ::: "memory");
        else        asm volatile("s_waitcnt lgkmcnt(0)" ::: "memory");
        __builtin_amdgcn_s_setprio(1);
#pragma unroll
        for (int kk = 0; kk < 2; ++kk)
#pragma unroll
            for (int mt = 0; mt < 4; ++mt)
#pragma unroll
                for (int nt = 0; nt < 2; ++nt)
                    acc[mt + 4][nt + 2] = __builtin_amdgcn_mfma_f32_16x16x32_bf16(
                        afh[mt][kk], bvh[nt][kk], acc[mt + 4][nt + 2], 0, 0, 0);
        __builtin_amdgcn_s_setprio(0);
        __builtin_amdgcn_s_barrier();

        // ---- P3 ----
        if (t + 2 < 16) STG(gB0, sBb, t + 2);
        __builtin_amdgcn_s_setprio(1);
#pragma unroll
        for (int kk = 0; kk < 2; ++kk)
#pragma unroll
            for (int mt = 0; mt < 4; ++mt)
#pragma unroll
                for (int nt = 0; nt < 2; ++nt)
                    acc[mt][nt + 2] = __builtin_amdgcn_mfma_f32_16x16x32_bf16(
                        afl[mt][kk], bvh[nt][kk], acc[mt][nt + 2], 0, 0, 0);
        __builtin_amdgcn_s_setprio(0);

        if (t < 15) {
#pragma unroll
            for (int nt = 0; nt < 2; ++nt) {
                bvl[nt][0] = bvln[nt][0];
                bvl[nt][1] = bvln[nt][1];
            }
        }
    }
#undef STG

#pragma unroll
    for (int mt = 0; mt < 8; ++mt) {
#pragma unroll
        for (int nt = 0; nt < 4; ++nt) {
            const int col = n0 + wc * 64 + nt * 16 + lr;
#pragma unroll
            for (int i = 0; i < 4; ++i) {
                const int row = m0 + wr * 128 + mt * 16 + lg * 4 + i;
                Cout[(size_t)row * 1024 + col] =
                    acc[mt][nt][i] + bias[col] + resid[(size_t)row * 1024 + col];
            }
        }
    }
}

// =====================================================================
// KV partials + fused Ksum partials; 8 n-splits (512 blocks, 2/CU).
// KVTp[sp][bh][e][d] over 512 ctx rows each; Ksump[sp][bh][d].
// =====================================================================
__global__ __launch_bounds__(256) void kv_kernel(
    const unsigned short* __restrict__ VT, const unsigned short* __restrict__ KT,
    float* __restrict__ KVTp, float* __restrict__ Ksump)
{
    const int bh = blockIdx.x, sp = blockIdx.y;   // 64 x 8
    const int b = bh >> 4, h = bh & 15;
    const int tid = threadIdx.x, lane = tid & 63, w = tid >> 6;
    const int lr = lane & 15, lg = lane >> 4;

    f32x4 acc[4][4];
#pragma unroll
    for (int i = 0; i < 4; ++i)
#pragma unroll
        for (int j = 0; j < 4; ++j)
#pragma unroll
            for (int e = 0; e < 4; ++e) acc[i][j][e] = 0.0f;
    float kp[4] = {0.0f, 0.0f, 0.0f, 0.0f};

    const size_t colbase = (size_t)b * 4096 + sp * 512 + w * 128 + lg * 8;
    const unsigned short* va = VT + (size_t)(h * 64 + lr) * NROW + colbase;
    const unsigned short* ka = KT + (size_t)(h * 64 + lr) * NROW + colbase;

    for (int ks = 0; ks < 4; ++ks) {
        short8 af[4], bfv[4];
#pragma unroll
        for (int mt = 0; mt < 4; ++mt)
            af[mt] = *(const short8*)(va + (size_t)mt * 16 * NROW + ks * 32);
#pragma unroll
        for (int nt = 0; nt < 4; ++nt)
            bfv[nt] = *(const short8*)(ka + (size_t)nt * 16 * NROW + ks * 32);
#pragma unroll
        for (int mt = 0; mt < 4; ++mt)
#pragma unroll
            for (int nt = 0; nt < 4; ++nt)
                acc[mt][nt] = __builtin_amdgcn_mfma_f32_16x16x32_bf16(
                    af[mt], bfv[nt], acc[mt][nt], 0, 0, 0);
#pragma unroll
        for (int nt = 0; nt < 4; ++nt)
#pragma unroll
            for (int j = 0; j < 8; ++j)
                kp[nt] += bf2f((unsigned short)bfv[nt][j]);
    }

#pragma unroll
    for (int nt = 0; nt < 4; ++nt) {
        kp[nt] += __shfl_xor(kp[nt], 16);
        kp[nt] += __shfl_xor(kp[nt], 32);
    }
    __shared__ float kred[4][64];
    if (lane < 16) {
#pragma unroll
        for (int nt = 0; nt < 4; ++nt) kred[w][nt * 16 + lane] = kp[nt];
    }

    __shared__ float red4[4][4096];
#pragma unroll
    for (int mt = 0; mt < 4; ++mt)
#pragma unroll
        for (int nt = 0; nt < 4; ++nt)
#pragma unroll
            for (int i = 0; i < 4; ++i)
                red4[w][(mt * 16 + lg * 4 + i) * 64 + nt * 16 + lr] = acc[mt][nt][i];
    __syncthreads();
    float* out = KVTp + ((size_t)sp * 64 + bh) * 4096;
    for (int i = tid; i < 4096; i += 256)
        out[i] = red4[0][i] + red4[1][i] + red4[2][i] + red4[3][i];
    if (tid < 64)
        Ksump[((size_t)sp * 64 + bh) * 64 + tid] =
            kred[0][tid] + kred[1][tid] + kred[2][tid] + kred[3][tid];
}

// =====================================================================
// A2[n][h*64+e] = (sum_d Q[n][h*64+d] * KV[d][e]) * invZ(n,h), z fused:
// z = sum_d Q[n][h*64+d] * Ksum[bh][d] computed from the same A-frags.
// =====================================================================
__global__ __launch_bounds__(256) void a2_kernel(
    const unsigned short* __restrict__ Q, const float* __restrict__ KVTp,
    const float* __restrict__ Ksump, unsigned short* __restrict__ A2)
{
    const int m0 = blockIdx.x * 128, h = blockIdx.y;
    const int b = m0 >> 12, bh = (b << 4) + h;
    const int tid = threadIdx.x, lane = tid & 63, w = tid >> 6;
    const int wr = w >> 1, wc = w & 1;
    const int lr = lane & 15, lg = lane >> 4;

    // Ksum[bh][0..63] summed over 8 splits
    __shared__ float ksum_s[64];
    if (tid < 64) {
        float s = 0.0f;
#pragma unroll
        for (int sp = 0; sp < 8; ++sp)
            s += Ksump[((size_t)sp * 64 + bh) * 64 + tid];
        ksum_s[tid] = s;
    }
    __syncthreads();

    f32x4 acc[4][2];
#pragma unroll
    for (int i = 0; i < 4; ++i)
#pragma unroll
        for (int j = 0; j < 2; ++j)
#pragma unroll
            for (int e = 0; e < 4; ++e) acc[i][j][e] = 0.0f;
    float zp[4] = {0.0f, 0.0f, 0.0f, 0.0f};

    const unsigned short* qa = Q + (size_t)(m0 + wr * 64 + lr) * DDIM + h * 64 + lg * 8;
    const float* kvb = KVTp + (size_t)bh * 4096 + (wc * 32 + lr) * 64 + lg * 8;

#pragma unroll
    for (int ks = 0; ks < 2; ++ks) {
        short8 af[4];
#pragma unroll
        for (int mt = 0; mt < 4; ++mt)
            af[mt] = *(const short8*)(qa + (size_t)mt * 16 * DDIM + ks * 32);
        // z partials: lane's 8 q-values at d = ks*32 + lg*8 + j for row mt*16+lr
#pragma unroll
        for (int mt = 0; mt < 4; ++mt)
#pragma unroll
            for (int j = 0; j < 8; ++j)
                zp[mt] += bf2f((unsigned short)af[mt][j]) * ksum_s[ks * 32 + lg * 8 + j];
        short8 bfv[2];
#pragma unroll
        for (int nt = 0; nt < 2; ++nt) {
            const float* p = kvb + nt * 16 * 64 + ks * 32;
            short8 t;
#pragma unroll
            for (int j = 0; j < 8; ++j) {
                float v = 0.0f;
#pragma unroll
                for (int sp = 0; sp < 8; ++sp) v += p[j + sp * 262144];
                t[j] = (short)f2bf(v);
            }
            bfv[nt] = t;
        }
#pragma unroll
        for (int mt = 0; mt < 4; ++mt)
#pragma unroll
            for (int nt = 0; nt < 2; ++nt)
                acc[mt][nt] = __builtin_amdgcn_mfma_f32_16x16x32_bf16(
                    af[mt], bfv[nt], acc[mt][nt], 0, 0, 0);
    }

    // complete z: sum over lg (lanes xor 16, 32 share lr) -> invZ per row
    float zinv[4];
#pragma unroll
    for (int mt = 0; mt < 4; ++mt) {
        zp[mt] += __shfl_xor(zp[mt], 16);
        zp[mt] += __shfl_xor(zp[mt], 32);
        zinv[mt] = 1.0f / fmaxf(zp[mt], 1e-6f);
    }

#pragma unroll
    for (int mt = 0; mt < 4; ++mt)
#pragma unroll
        for (int nt = 0; nt < 2; ++nt)
#pragma unroll
            for (int i = 0; i < 4; ++i) {
                const int row = m0 + wr * 64 + mt * 16 + lg * 4 + i;
                const int col = h * 64 + wc * 32 + nt * 16 + lr;
                // z for C-row (lg*4+i) lives at lane lr == lg*4+i (any lg')
                const float zi = __shfl(zinv[mt], lg * 4 + i);
                const float v = acc[mt][nt][i] * zi;
                A2[(size_t)row * DDIM + col] = f2bf(v);
            }
}

// =====================================================================
// host
// =====================================================================
extern "C" void kernel_launch(void* const* d_in, const int* in_sizes, int n_in,
                              void* d_out, int out_size, void* d_ws, size_t ws_size,
                              hipStream_t stream)
{
    const float* query   = (const float*)d_in[0];
    const float* context = (const float*)d_in[1];
    const float* q_w = (const float*)d_in[2];
    const float* q_b = (const float*)d_in[3];
    const float* k_w = (const float*)d_in[4];
    const float* k_b = (const float*)d_in[5];
    const float* v_w = (const float*)d_in[6];
    const float* v_b = (const float*)d_in[7];
    const float* o_w = (const float*)d_in[8];
    const float* o_b = (const float*)d_in[9];
    const float* lnq_g = (const float*)d_in[10];
    const float* lnq_b = (const float*)d_in[11];
    const float* lnk_g = (const float*)d_in[12];
    const float* lnk_b = (const float*)d_in[13];

    char* ws = (char*)d_ws;
    unsigned short* WQ  = (unsigned short*)(ws);                    // 2 MiB
    unsigned short* WKV = (unsigned short*)(ws + (2u << 20));       // WK;WV 4 MiB
    unsigned short* WO  = (unsigned short*)(ws + (6u << 20));
    unsigned short* QLN = (unsigned short*)(ws + (8u << 20));       // 32 MiB
    unsigned short* CLN = (unsigned short*)(ws + (40u << 20));
    unsigned short* Qm  = (unsigned short*)(ws + (72u << 20));
    unsigned short* KT  = (unsigned short*)(ws + (104u << 20));     // rows 0-1023 of KVT
    unsigned short* VT  = (unsigned short*)(ws + (136u << 20));     // rows 1024-2047
    float* KVTp  = (float*)(ws + (168u << 20));                     // 8 MiB (8 splits)
    float* Ksump = (float*)(ws + (176u << 20));                     // 128 KiB
    unsigned short* A2 = QLN;                                       // alias

    ln_kernel<<<2 * NROW + 4096, 256, 0, stream>>>(
        query, context, lnq_g, lnq_b, lnk_g, lnk_b, QLN, CLN,
        q_w, k_w, v_w, o_w, WQ);
    gemm_qkv<<<3072, 256, 0, stream>>>(QLN, WQ, CLN, WKV, Qm, KT,
                                       q_b, k_b, v_b);
    kv_kernel<<<dim3(64, 8), 256, 0, stream>>>(VT, KT, KVTp, Ksump);
    a2_kernel<<<dim3(128, 16), 256, 0, stream>>>(Qm, KVTp, Ksump, A2);
    gemm_out256<<<256, 512, 0, stream>>>(A2, WO, (float*)d_out, o_b, query);
}

// Round 12
// 277.940 us; speedup vs baseline: 1.1457x; 1.1457x over previous
//
#include <hip/hip_runtime.h>

#define DEV __device__ __forceinline__

typedef __attribute__((ext_vector_type(8))) short short8;
typedef __attribute__((ext_vector_type(4))) short short4v;
typedef __attribute__((ext_vector_type(4))) float f32x4;

// ---------- bf16 helpers ----------
DEV float bf2f(unsigned short u) { return __uint_as_float(((unsigned int)u) << 16); }
DEV unsigned short f2bf(float f) {
    unsigned int u = __float_as_uint(f);
    u += 0x7FFFu + ((u >> 16) & 1u);   // RNE
    return (unsigned short)(u >> 16);
}

DEV float elu1(float v) { return v > 0.0f ? v + 1.0f : __expf(v); }

// ---------- async global->LDS, 16B per lane ----------
DEV void gload_lds16(const void* g, void* l) {
    __builtin_amdgcn_global_load_lds(
        (__attribute__((address_space(1))) unsigned int*)(g),
        (__attribute__((address_space(3))) unsigned int*)(l),
        16, 0, 0);
}

// Problem constants: B=4, NQ=NC=4096, D=1024, H=16, HD=64
#define NROW 16384
#define DDIM 1024

// =====================================================================
// LayerNorm (rows 0..2*NROW-1) + weight-convert (blocks >= 2*NROW).
// =====================================================================
__global__ __launch_bounds__(256) void ln_kernel(
    const float* __restrict__ query, const float* __restrict__ context,
    const float* __restrict__ lnq_g, const float* __restrict__ lnq_b,
    const float* __restrict__ lnk_g, const float* __restrict__ lnk_b,
    unsigned short* __restrict__ qln, unsigned short* __restrict__ cln,
    const float* __restrict__ q_w, const float* __restrict__ k_w,
    const float* __restrict__ v_w, const float* __restrict__ o_w,
    unsigned short* __restrict__ wout)
{
    const int tid = threadIdx.x;
    if (blockIdx.x >= 2 * NROW) {
        const int i = (blockIdx.x - 2 * NROW) * 256 + tid;
        const int mat = i >> 18;
        const int idx = (i & 262143) * 4;
        const float* src = mat == 0 ? q_w : mat == 1 ? k_w : mat == 2 ? v_w : o_w;
        f32x4 v = *(const f32x4*)(src + idx);
        short4v o;
#pragma unroll
        for (int j = 0; j < 4; ++j) o[j] = (short)f2bf(v[j]);
        *(short4v*)(wout + (size_t)mat * 1048576 + idx) = o;
        return;
    }

    const int row = blockIdx.x;
    const bool isq = row < NROW;
    const int r = isq ? row : row - NROW;
    const float* src = (isq ? query : context) + (size_t)r * DDIM;
    const float* g   = isq ? lnq_g : lnk_g;
    const float* bb  = isq ? lnq_b : lnk_b;
    unsigned short* dst = (isq ? qln : cln) + (size_t)r * DDIM;

    f32x4 x = *(const f32x4*)(src + tid * 4);
    float s  = x[0] + x[1] + x[2] + x[3];
    float sq = x[0]*x[0] + x[1]*x[1] + x[2]*x[2] + x[3]*x[3];
#pragma unroll
    for (int off = 32; off; off >>= 1) {
        s  += __shfl_xor(s, off);
        sq += __shfl_xor(sq, off);
    }
    __shared__ float red[8];
    const int lane = tid & 63, w = tid >> 6;
    if (lane == 0) { red[w] = s; red[4 + w] = sq; }
    __syncthreads();
    s  = red[0] + red[1] + red[2] + red[3];
    sq = red[4] + red[5] + red[6] + red[7];
    const float mu  = s * (1.0f / DDIM);
    const float var = sq * (1.0f / DDIM) - mu * mu;
    const float rstd = rsqrtf(var + 1e-5f);

    f32x4 gv = *(const f32x4*)(g + tid * 4);
    f32x4 bv = *(const f32x4*)(bb + tid * 4);
    short4v o;
#pragma unroll
    for (int j = 0; j < 4; ++j)
        o[j] = (short)f2bf((x[j] - mu) * rstd * gv[j] + bv[j]);
    *(short4v*)(dst + tid * 4) = o;
}

// =====================================================================
// 128x128-tile GEMM core (round-9 verified: 0 conflicts, occ 36%, 736 TF)
// =====================================================================
template <typename EPI>
DEV void gemm128(unsigned short* __restrict__ sA,
                 unsigned short* __restrict__ sB,
                 const unsigned short* __restrict__ Ap,
                 const unsigned short* __restrict__ Bp,
                 int m0, int n0, EPI epi)
{
    const int tid = threadIdx.x;
    const int lane = tid & 63, w = tid >> 6;
    const int wr = w >> 1, wc = w & 1;
    const int lr = lane & 15, lg = lane >> 4;

    const int srow = tid >> 3;
    const int cswz = (tid & 7) ^ (srow & 7);
    const unsigned short* gA0 = Ap + (size_t)(m0 + srow) * 1024 + cswz * 8;
    const unsigned short* gB0 = Bp + (size_t)(n0 + srow) * 1024 + cswz * 8;
    unsigned short* dA = sA + tid * 8;
    unsigned short* dB = sB + tid * 8;

    const int sw0 = ((0 + lg) ^ (lr & 7)) * 8;
    const int sw1 = ((4 + lg) ^ (lr & 7)) * 8;

    f32x4 acc[4][4];
#pragma unroll
    for (int i = 0; i < 4; ++i)
#pragma unroll
        for (int j = 0; j < 4; ++j)
#pragma unroll
            for (int e = 0; e < 4; ++e) acc[i][j][e] = 0.0f;

#define STG8(T)                                                               \
    {                                                                         \
        const int ko = (T) * 64;                                              \
        _Pragma("unroll")                                                     \
        for (int j = 0; j < 4; ++j) {                                         \
            gload_lds16(gA0 + ko + (size_t)j * 32768, dA + j * 2048);         \
            gload_lds16(gB0 + ko + (size_t)j * 32768, dB + j * 2048);         \
        }                                                                     \
    }

    STG8(0);
    for (int t = 0; t < 16; ++t) {
        asm volatile("s_waitcnt vmcnt(0)" ::: "memory");
        __builtin_amdgcn_s_barrier();

        short8 af[4], bf[4];
#pragma unroll
        for (int mt = 0; mt < 4; ++mt)
            af[mt] = *(const short8*)&sA[(wr * 64 + mt * 16 + lr) * 64 + sw0];
#pragma unroll
        for (int nt = 0; nt < 4; ++nt)
            bf[nt] = *(const short8*)&sB[(wc * 64 + nt * 16 + lr) * 64 + sw0];
        __builtin_amdgcn_s_setprio(1);
#pragma unroll
        for (int mt = 0; mt < 4; ++mt)
#pragma unroll
            for (int nt = 0; nt < 4; ++nt)
                acc[mt][nt] = __builtin_amdgcn_mfma_f32_16x16x32_bf16(
                    af[mt], bf[nt], acc[mt][nt], 0, 0, 0);
        __builtin_amdgcn_s_setprio(0);

#pragma unroll
        for (int mt = 0; mt < 4; ++mt)
            af[mt] = *(const short8*)&sA[(wr * 64 + mt * 16 + lr) * 64 + sw1];
#pragma unroll
        for (int nt = 0; nt < 4; ++nt)
            bf[nt] = *(const short8*)&sB[(wc * 64 + nt * 16 + lr) * 64 + sw1];
        asm volatile("s_waitcnt lgkmcnt(0)" ::: "memory");
        __builtin_amdgcn_s_barrier();
        if (t < 15) STG8(t + 1);
        __builtin_amdgcn_s_setprio(1);
#pragma unroll
        for (int mt = 0; mt < 4; ++mt)
#pragma unroll
            for (int nt = 0; nt < 4; ++nt)
                acc[mt][nt] = __builtin_amdgcn_mfma_f32_16x16x32_bf16(
                    af[mt], bf[nt], acc[mt][nt], 0, 0, 0);
        __builtin_amdgcn_s_setprio(0);
    }
#undef STG8

#pragma unroll
    for (int mt = 0; mt < 4; ++mt)
#pragma unroll
        for (int nt = 0; nt < 4; ++nt) {
            const int col = n0 + wc * 64 + nt * 16 + lr;
#pragma unroll
            for (int i = 0; i < 4; ++i) {
                const int row = m0 + wr * 64 + mt * 16 + lg * 4 + i;
                epi(row, col, acc[mt][nt][i]);
            }
        }
}

// ---- merged projections: Q-proj (1024 tiles) + KV-proj (2048 tiles) ----
__global__ __launch_bounds__(256, 4) void gemm_qkv(
    const unsigned short* __restrict__ QLN, const unsigned short* __restrict__ WQ,
    const unsigned short* __restrict__ CLN, const unsigned short* __restrict__ WKV,
    unsigned short* __restrict__ Qm, unsigned short* __restrict__ KVT,
    const float* __restrict__ q_b, const float* __restrict__ k_b,
    const float* __restrict__ v_b)
{
    __shared__ __attribute__((aligned(16))) unsigned short sA[128 * 64];
    __shared__ __attribute__((aligned(16))) unsigned short sB[128 * 64];

    const int bid = blockIdx.x;                  // 3072 blocks
    const int l = (bid & 7) * 384 + (bid >> 3);  // XCD-chunked

    if (l < 1024) {
        const int m0 = (l >> 3) * 128, n0 = (l & 7) * 128;
        gemm128(sA, sB, QLN, WQ, m0, n0,
            [&](int row, int col, float v) {
                v = elu1(v + q_b[col]);
                Qm[(size_t)row * 1024 + col] = f2bf(v);
            });
    } else {
        const int r = l - 1024;                  // 0..2047
        const int m0 = (r & 15) * 128, n0 = (r >> 4) * 128;
        gemm128(sA, sB, WKV, CLN, m0, n0,
            [&](int row, int col, float v) {
                if (row < 1024) v = elu1(v + k_b[row]);
                else            v = v + v_b[row - 1024];
                KVT[(size_t)row * NROW + col] = f2bf(v);
            });
    }
}

// =====================================================================
// O-projection: round-5 deep-pipelined 256x256/BK=64/8-wave kernel.
// =====================================================================
__global__ __launch_bounds__(512, 2) void gemm_out256(
    const unsigned short* __restrict__ A, const unsigned short* __restrict__ Bm,
    float* __restrict__ Cout, const float* __restrict__ bias,
    const float* __restrict__ resid)
{
    __shared__ __attribute__((aligned(16))) unsigned short smem[65536];
    unsigned short* sAb = smem;           // 2 x 16384
    unsigned short* sBb = smem + 32768;   // 2 x 16384

    const int bid = blockIdx.x;           // 256 blocks
    const int l = (bid & 7) * 32 + (bid >> 3);
    const int m0 = (l >> 2) * 256, n0 = (l & 3) * 256;

    const int tid = threadIdx.x;
    const int lane = tid & 63, w = tid >> 6;
    const int wr = w >> 2, wc = w & 3;          // 2 x 4 wave grid
    const int lr = lane & 15, lg = lane >> 4;

    const int srow = tid >> 3;
    const int cswz = (tid & 7) ^ (srow & 7);
    const unsigned short* gA0 = A  + (size_t)(m0 + srow) * 1024 + cswz * 8;
    const unsigned short* gB0 = Bm + (size_t)(n0 + srow) * 1024 + cswz * 8;

    const int sw0 = ((0 + lg) ^ (lr & 7)) * 8;
    const int sw1 = ((4 + lg) ^ (lr & 7)) * 8;

    f32x4 acc[8][4];
#pragma unroll
    for (int i = 0; i < 8; ++i)
#pragma unroll
        for (int j = 0; j < 4; ++j)
#pragma unroll
            for (int e = 0; e < 4; ++e) acc[i][j][e] = 0.0f;

#define STG(GP, SP, T)                                                        \
    {                                                                         \
        const unsigned short* g = (GP) + (T) * 64;                            \
        unsigned short* d = (SP) + ((T) & 1) * 16384 + tid * 8;               \
        _Pragma("unroll")                                                     \
        for (int L = 0; L < 4; ++L)                                           \
            gload_lds16(g + (size_t)L * 65536, d + L * 4096);                 \
    }

    STG(gB0, sBb, 0); STG(gA0, sAb, 0); STG(gB0, sBb, 1); STG(gA0, sAb, 1);
    asm volatile("s_waitcnt vmcnt(8)" ::: "memory");
    __builtin_amdgcn_s_barrier();

    short8 bvl[2][2];
#pragma unroll
    for (int nt = 0; nt < 2; ++nt) {
        const int rb = (wc * 64 + nt * 16 + lr) * 64;
        bvl[nt][0] = *(const short8*)&sBb[rb + sw0];
        bvl[nt][1] = *(const short8*)&sBb[rb + sw1];
    }

    for (int t = 0; t < 16; ++t) {
        const unsigned short* bA = sAb + (t & 1) * 16384;
        const unsigned short* bB = sBb + (t & 1) * 16384;
        const unsigned short* bBn = sBb + ((t + 1) & 1) * 16384;
        short8 afl[4][2], afh[4][2], bvh[2][2], bvln[2][2];

        // ---- P0 ----
#pragma unroll
        for (int mt = 0; mt < 4; ++mt) {
            const int ra = (wr * 128 + mt * 16 + lr) * 64;
            afl[mt][0] = *(const short8*)&bA[ra + sw0];
            afl[mt][1] = *(const short8*)&bA[ra + sw1];
        }
#pragma unroll
        for (int mt = 0; mt < 4; ++mt) {
            const int ra = (wr * 128 + (mt + 4) * 16 + lr) * 64;
            afh[mt][0] = *(const short8*)&bA[ra + sw0];
            afh[mt][1] = *(const short8*)&bA[ra + sw1];
        }
        asm volatile("s_waitcnt lgkmcnt(8)" ::: "memory");
        __builtin_amdgcn_s_setprio(1);
#pragma unroll
        for (int kk = 0; kk < 2; ++kk)
#pragma unroll
            for (int mt = 0; mt < 4; ++mt)
#pragma unroll
                for (int nt = 0; nt < 2; ++nt)
                    acc[mt][nt] = __builtin_amdgcn_mfma_f32_16x16x32_bf16(
                        afl[mt][kk], bvl[nt][kk], acc[mt][nt], 0, 0, 0);
        __builtin_amdgcn_s_setprio(0);
        __builtin_amdgcn_s_barrier();

        // ---- P1 ----
#pragma unroll
        for (int nt = 0; nt < 2; ++nt) {
            const int rb = (wc * 64 + (nt + 2) * 16 + lr) * 64;
            bvh[nt][0] = *(const short8*)&bB[rb + sw0];
            bvh[nt][1] = *(const short8*)&bB[rb + sw1];
        }
        asm volatile("s_waitcnt lgkmcnt(4)" ::: "memory");
        __builtin_amdgcn_s_setprio(1);
#pragma unroll
        for (int kk = 0; kk < 2; ++kk)
#pragma unroll
            for (int mt = 0; mt < 4; ++mt)
#pragma unroll
                for (int nt = 0; nt < 2; ++nt)
                    acc[mt + 4][nt] = __builtin_amdgcn_mfma_f32_16x16x32_bf16(
                        afh[mt][kk], bvl[nt][kk], acc[mt + 4][nt], 0, 0, 0);
        __builtin_amdgcn_s_setprio(0);
        asm volatile("s_waitcnt vmcnt(0)" ::: "memory");
        __builtin_amdgcn_s_barrier();

        // ---- P2 ----
        if (t < 15) {
#pragma unroll
            for (int nt = 0; nt < 2; ++nt) {
                const int rb = (wc * 64 + nt * 16 + lr) * 64;
                bvln[nt][0] = *(const short8*)&bBn[rb + sw0];
                bvln[nt][1] = *(const short8*)&bBn[rb + sw1];
            }
        }
        if (t + 2 < 16) STG(gA0, sAb, t + 2);
        if (t < 15) asm volatile("s_waitcnt lgkmcnt(4)" ::: "memory");
        else        asm volatile("s_waitcnt lgkmcnt(0)" ::: "memory");
        __builtin_amdgcn_s_setprio(1);
#pragma unroll
        for (int kk = 0; kk < 2; ++kk)
#pragma unroll
            for (int mt = 0; mt < 4; ++mt)
#pragma unroll
                for (int nt = 0; nt < 2; ++nt)
                    acc[mt + 4][nt + 2] = __builtin_amdgcn_mfma_f32_16x16x32_bf16(
                        afh[mt][kk], bvh[nt][kk], acc[mt + 4][nt + 2], 0, 0, 0);
        __builtin_amdgcn_s_setprio(0);
        __builtin_amdgcn_s_barrier();

        // ---- P3 ----
        if (t + 2 < 16) STG(gB0, sBb, t + 2);
        __builtin_amdgcn_s_setprio(1);
#pragma unroll
        for (int kk = 0; kk < 2; ++kk)
#pragma unroll
            for (int mt = 0; mt < 4; ++mt)
#pragma unroll
                for (int nt = 0; nt < 2; ++nt)
                    acc[mt][nt + 2] = __builtin_amdgcn_mfma_f32_16x16x32_bf16(
                        afl[mt][kk], bvh[nt][kk], acc[mt][nt + 2], 0, 0, 0);
        __builtin_amdgcn_s_setprio(0);

        if (t < 15) {
#pragma unroll
            for (int nt = 0; nt < 2; ++nt) {
                bvl[nt][0] = bvln[nt][0];
                bvl[nt][1] = bvln[nt][1];
            }
        }
    }
#undef STG

#pragma unroll
    for (int mt = 0; mt < 8; ++mt) {
#pragma unroll
        for (int nt = 0; nt < 4; ++nt) {
            const int col = n0 + wc * 64 + nt * 16 + lr;
#pragma unroll
            for (int i = 0; i < 4; ++i) {
                const int row = m0 + wr * 128 + mt * 16 + lg * 4 + i;
                Cout[(size_t)row * 1024 + col] =
                    acc[mt][nt][i] + bias[col] + resid[(size_t)row * 1024 + col];
            }
        }
    }
}

// =====================================================================
// KV partials + fused Ksum partials; 8 n-splits (512 blocks, 2/CU).
// =====================================================================
__global__ __launch_bounds__(256) void kv_kernel(
    const unsigned short* __restrict__ VT, const unsigned short* __restrict__ KT,
    float* __restrict__ KVTp, float* __restrict__ Ksump)
{
    const int bh = blockIdx.x, sp = blockIdx.y;   // 64 x 8
    const int b = bh >> 4, h = bh & 15;
    const int tid = threadIdx.x, lane = tid & 63, w = tid >> 6;
    const int lr = lane & 15, lg = lane >> 4;

    f32x4 acc[4][4];
#pragma unroll
    for (int i = 0; i < 4; ++i)
#pragma unroll
        for (int j = 0; j < 4; ++j)
#pragma unroll
            for (int e = 0; e < 4; ++e) acc[i][j][e] = 0.0f;
    float kp[4] = {0.0f, 0.0f, 0.0f, 0.0f};

    const size_t colbase = (size_t)b * 4096 + sp * 512 + w * 128 + lg * 8;
    const unsigned short* va = VT + (size_t)(h * 64 + lr) * NROW + colbase;
    const unsigned short* ka = KT + (size_t)(h * 64 + lr) * NROW + colbase;

    for (int ks = 0; ks < 4; ++ks) {
        short8 af[4], bfv[4];
#pragma unroll
        for (int mt = 0; mt < 4; ++mt)
            af[mt] = *(const short8*)(va + (size_t)mt * 16 * NROW + ks * 32);
#pragma unroll
        for (int nt = 0; nt < 4; ++nt)
            bfv[nt] = *(const short8*)(ka + (size_t)nt * 16 * NROW + ks * 32);
#pragma unroll
        for (int mt = 0; mt < 4; ++mt)
#pragma unroll
            for (int nt = 0; nt < 4; ++nt)
                acc[mt][nt] = __builtin_amdgcn_mfma_f32_16x16x32_bf16(
                    af[mt], bfv[nt], acc[mt][nt], 0, 0, 0);
#pragma unroll
        for (int nt = 0; nt < 4; ++nt)
#pragma unroll
            for (int j = 0; j < 8; ++j)
                kp[nt] += bf2f((unsigned short)bfv[nt][j]);
    }

#pragma unroll
    for (int nt = 0; nt < 4; ++nt) {
        kp[nt] += __shfl_xor(kp[nt], 16);
        kp[nt] += __shfl_xor(kp[nt], 32);
    }
    __shared__ float kred[4][64];
    if (lane < 16) {
#pragma unroll
        for (int nt = 0; nt < 4; ++nt) kred[w][nt * 16 + lane] = kp[nt];
    }

    __shared__ float red4[4][4096];
#pragma unroll
    for (int mt = 0; mt < 4; ++mt)
#pragma unroll
        for (int nt = 0; nt < 4; ++nt)
#pragma unroll
            for (int i = 0; i < 4; ++i)
                red4[w][(mt * 16 + lg * 4 + i) * 64 + nt * 16 + lr] = acc[mt][nt][i];
    __syncthreads();
    float* out = KVTp + ((size_t)sp * 64 + bh) * 4096;
    for (int i = tid; i < 4096; i += 256)
        out[i] = red4[0][i] + red4[1][i] + red4[2][i] + red4[3][i];
    if (tid < 64)
        Ksump[((size_t)sp * 64 + bh) * 64 + tid] =
            kred[0][tid] + kred[1][tid] + kred[2][tid] + kred[3][tid];
}

// =====================================================================
// Reduce the 8 split-partials once: KVs[bh][4096], Ks[bh][64].
// 64 blocks; 8.1 MB L2-resident reads -> ~3 us.
// =====================================================================
__global__ __launch_bounds__(256) void kvred_kernel(
    const float* __restrict__ KVTp, const float* __restrict__ Ksump,
    float* __restrict__ KVs, float* __restrict__ Ks)
{
    const int bh = blockIdx.x;
    const int tid = threadIdx.x;
    for (int i = tid * 4; i < 4096; i += 1024) {
        f32x4 s = {0.0f, 0.0f, 0.0f, 0.0f};
#pragma unroll
        for (int sp = 0; sp < 8; ++sp) {
            f32x4 v = *(const f32x4*)(KVTp + ((size_t)sp * 64 + bh) * 4096 + i);
            s[0] += v[0]; s[1] += v[1]; s[2] += v[2]; s[3] += v[3];
        }
        *(f32x4*)(KVs + (size_t)bh * 4096 + i) = s;
    }
    if (tid < 64) {
        float s = 0.0f;
#pragma unroll
        for (int sp = 0; sp < 8; ++sp)
            s += Ksump[((size_t)sp * 64 + bh) * 64 + tid];
        Ks[bh * 64 + tid] = s;
    }
}

// =====================================================================
// A2[n][h*64+e] = (sum_d Q[n][h*64+d] * KV[d][e]) * invZ(n,h); z fused.
// KV fragments now vector-loaded from pre-reduced KVs (f32x4 x2).
// =====================================================================
__global__ __launch_bounds__(256) void a2_kernel(
    const unsigned short* __restrict__ Q, const float* __restrict__ KVs,
    const float* __restrict__ Ks, unsigned short* __restrict__ A2)
{
    const int m0 = blockIdx.x * 128, h = blockIdx.y;
    const int b = m0 >> 12, bh = (b << 4) + h;
    const int tid = threadIdx.x, lane = tid & 63, w = tid >> 6;
    const int wr = w >> 1, wc = w & 1;
    const int lr = lane & 15, lg = lane >> 4;

    __shared__ float ksum_s[64];
    if (tid < 64) ksum_s[tid] = Ks[bh * 64 + tid];
    __syncthreads();

    f32x4 acc[4][2];
#pragma unroll
    for (int i = 0; i < 4; ++i)
#pragma unroll
        for (int j = 0; j < 2; ++j)
#pragma unroll
            for (int e = 0; e < 4; ++e) acc[i][j][e] = 0.0f;
    float zp[4] = {0.0f, 0.0f, 0.0f, 0.0f};

    const unsigned short* qa = Q + (size_t)(m0 + wr * 64 + lr) * DDIM + h * 64 + lg * 8;
    const float* kvb = KVs + (size_t)bh * 4096 + (wc * 32 + lr) * 64 + lg * 8;

#pragma unroll
    for (int ks = 0; ks < 2; ++ks) {
        short8 af[4];
#pragma unroll
        for (int mt = 0; mt < 4; ++mt)
            af[mt] = *(const short8*)(qa + (size_t)mt * 16 * DDIM + ks * 32);
#pragma unroll
        for (int mt = 0; mt < 4; ++mt)
#pragma unroll
            for (int j = 0; j < 8; ++j)
                zp[mt] += bf2f((unsigned short)af[mt][j]) * ksum_s[ks * 32 + lg * 8 + j];
        short8 bfv[2];
#pragma unroll
        for (int nt = 0; nt < 2; ++nt) {
            const float* p = kvb + nt * 16 * 64 + ks * 32;
            f32x4 v0 = *(const f32x4*)(p);
            f32x4 v1 = *(const f32x4*)(p + 4);
            short8 t;
#pragma unroll
            for (int j = 0; j < 4; ++j) {
                t[j]     = (short)f2bf(v0[j]);
                t[j + 4] = (short)f2bf(v1[j]);
            }
            bfv[nt] = t;
        }
#pragma unroll
        for (int mt = 0; mt < 4; ++mt)
#pragma unroll
            for (int nt = 0; nt < 2; ++nt)
                acc[mt][nt] = __builtin_amdgcn_mfma_f32_16x16x32_bf16(
                    af[mt], bfv[nt], acc[mt][nt], 0, 0, 0);
    }

    float zinv[4];
#pragma unroll
    for (int mt = 0; mt < 4; ++mt) {
        zp[mt] += __shfl_xor(zp[mt], 16);
        zp[mt] += __shfl_xor(zp[mt], 32);
        zinv[mt] = 1.0f / fmaxf(zp[mt], 1e-6f);
    }

#pragma unroll
    for (int mt = 0; mt < 4; ++mt)
#pragma unroll
        for (int nt = 0; nt < 2; ++nt)
#pragma unroll
            for (int i = 0; i < 4; ++i) {
                const int row = m0 + wr * 64 + mt * 16 + lg * 4 + i;
                const int col = h * 64 + wc * 32 + nt * 16 + lr;
                const float zi = __shfl(zinv[mt], lg * 4 + i);
                const float v = acc[mt][nt][i] * zi;
                A2[(size_t)row * DDIM + col] = f2bf(v);
            }
}

// =====================================================================
// host
// =====================================================================
extern "C" void kernel_launch(void* const* d_in, const int* in_sizes, int n_in,
                              void* d_out, int out_size, void* d_ws, size_t ws_size,
                              hipStream_t stream)
{
    const float* query   = (const float*)d_in[0];
    const float* context = (const float*)d_in[1];
    const float* q_w = (const float*)d_in[2];
    const float* q_b = (const float*)d_in[3];
    const float* k_w = (const float*)d_in[4];
    const float* k_b = (const float*)d_in[5];
    const float* v_w = (const float*)d_in[6];
    const float* v_b = (const float*)d_in[7];
    const float* o_w = (const float*)d_in[8];
    const float* o_b = (const float*)d_in[9];
    const float* lnq_g = (const float*)d_in[10];
    const float* lnq_b = (const float*)d_in[11];
    const float* lnk_g = (const float*)d_in[12];
    const float* lnk_b = (const float*)d_in[13];

    char* ws = (char*)d_ws;
    unsigned short* WQ  = (unsigned short*)(ws);                    // 2 MiB
    unsigned short* WKV = (unsigned short*)(ws + (2u << 20));       // WK;WV 4 MiB
    unsigned short* WO  = (unsigned short*)(ws + (6u << 20));
    unsigned short* QLN = (unsigned short*)(ws + (8u << 20));       // 32 MiB
    unsigned short* CLN = (unsigned short*)(ws + (40u << 20));
    unsigned short* Qm  = (unsigned short*)(ws + (72u << 20));
    unsigned short* KT  = (unsigned short*)(ws + (104u << 20));     // rows 0-1023 of KVT
    unsigned short* VT  = (unsigned short*)(ws + (136u << 20));     // rows 1024-2047
    float* KVTp  = (float*)(ws + (168u << 20));                     // 8 MiB (8 splits)
    float* Ksump = (float*)(ws + (176u << 20));                     // 128 KiB
    float* KVs   = (float*)(ws + (177u << 20));                     // 1 MiB
    float* Ks    = (float*)(ws + (178u << 20));                     // 16 KiB
    unsigned short* A2 = QLN;                                       // alias

    ln_kernel<<<2 * NROW + 4096, 256, 0, stream>>>(
        query, context, lnq_g, lnq_b, lnk_g, lnk_b, QLN, CLN,
        q_w, k_w, v_w, o_w, WQ);
    gemm_qkv<<<3072, 256, 0, stream>>>(QLN, WQ, CLN, WKV, Qm, KT,
                                       q_b, k_b, v_b);
    kv_kernel<<<dim3(64, 8), 256, 0, stream>>>(VT, KT, KVTp, Ksump);
    kvred_kernel<<<64, 256, 0, stream>>>(KVTp, Ksump, KVs, Ks);
    a2_kernel<<<dim3(128, 16), 256, 0, stream>>>(Qm, KVs, Ks, A2);
    gemm_out256<<<256, 512, 0, stream>>>(A2, WO, (float*)d_out, o_b, query);
}

// Round 13
// 265.197 us; speedup vs baseline: 1.2007x; 1.0480x over previous
//
#include <hip/hip_runtime.h>

#define DEV __device__ __forceinline__

typedef __attribute__((ext_vector_type(8))) short short8;
typedef __attribute__((ext_vector_type(4))) short short4v;
typedef __attribute__((ext_vector_type(4))) float f32x4;

// ---------- bf16 helpers ----------
DEV float bf2f(unsigned short u) { return __uint_as_float(((unsigned int)u) << 16); }
DEV unsigned short f2bf(float f) {
    unsigned int u = __float_as_uint(f);
    u += 0x7FFFu + ((u >> 16) & 1u);   // RNE
    return (unsigned short)(u >> 16);
}

DEV float elu1(float v) { return v > 0.0f ? v + 1.0f : __expf(v); }

// ---------- async global->LDS, 16B per lane ----------
DEV void gload_lds16(const void* g, void* l) {
    __builtin_amdgcn_global_load_lds(
        (__attribute__((address_space(1))) unsigned int*)(g),
        (__attribute__((address_space(3))) unsigned int*)(l),
        16, 0, 0);
}

// Problem constants: B=4, NQ=NC=4096, D=1024, H=16, HD=64
#define NROW 16384
#define DDIM 1024

// =====================================================================
// LayerNorm, wave-per-row (blocks 0..8191, 4 rows each) + weight
// convert (blocks >= 8192). No LDS, no __syncthreads: 64-lane shuffle
// reduce only; 16 f32 elems per lane.
// =====================================================================
__global__ __launch_bounds__(256) void ln_kernel(
    const float* __restrict__ query, const float* __restrict__ context,
    const float* __restrict__ lnq_g, const float* __restrict__ lnq_b,
    const float* __restrict__ lnk_g, const float* __restrict__ lnk_b,
    unsigned short* __restrict__ qln, unsigned short* __restrict__ cln,
    const float* __restrict__ q_w, const float* __restrict__ k_w,
    const float* __restrict__ v_w, const float* __restrict__ o_w,
    unsigned short* __restrict__ wout)
{
    const int tid = threadIdx.x;
    if (blockIdx.x >= 8192) {
        const int i = (blockIdx.x - 8192) * 256 + tid;
        const int mat = i >> 18;
        const int idx = (i & 262143) * 4;
        const float* src = mat == 0 ? q_w : mat == 1 ? k_w : mat == 2 ? v_w : o_w;
        f32x4 v = *(const f32x4*)(src + idx);
        short4v o;
#pragma unroll
        for (int j = 0; j < 4; ++j) o[j] = (short)f2bf(v[j]);
        *(short4v*)(wout + (size_t)mat * 1048576 + idx) = o;
        return;
    }

    const int lane = tid & 63, w = tid >> 6;
    const int row = blockIdx.x * 4 + w;          // 0..32767
    const bool isq = row < NROW;
    const int r = isq ? row : row - NROW;
    const float* src = (isq ? query : context) + (size_t)r * DDIM;
    const float* g   = isq ? lnq_g : lnk_g;
    const float* bb  = isq ? lnq_b : lnk_b;
    unsigned short* dst = (isq ? qln : cln) + (size_t)r * DDIM;

    f32x4 x[4];
    float s = 0.0f, sq = 0.0f;
#pragma unroll
    for (int j = 0; j < 4; ++j) {
        x[j] = *(const f32x4*)(src + j * 256 + lane * 4);
#pragma unroll
        for (int e = 0; e < 4; ++e) { s += x[j][e]; sq += x[j][e] * x[j][e]; }
    }
#pragma unroll
    for (int off = 32; off; off >>= 1) {
        s  += __shfl_xor(s, off);
        sq += __shfl_xor(sq, off);
    }
    const float mu  = s * (1.0f / DDIM);
    const float var = sq * (1.0f / DDIM) - mu * mu;
    const float rstd = rsqrtf(var + 1e-5f);

#pragma unroll
    for (int j = 0; j < 4; ++j) {
        f32x4 gv = *(const f32x4*)(g  + j * 256 + lane * 4);
        f32x4 bv = *(const f32x4*)(bb + j * 256 + lane * 4);
        short4v o;
#pragma unroll
        for (int e = 0; e < 4; ++e)
            o[e] = (short)f2bf((x[j][e] - mu) * rstd * gv[e] + bv[e]);
        *(short4v*)(dst + j * 256 + lane * 4) = o;
    }
}

// =====================================================================
// 128x128-tile GEMM core (round-9 verified: 0 conflicts, occ 36%, 736 TF)
// =====================================================================
template <typename EPI>
DEV void gemm128(unsigned short* __restrict__ sA,
                 unsigned short* __restrict__ sB,
                 const unsigned short* __restrict__ Ap,
                 const unsigned short* __restrict__ Bp,
                 int m0, int n0, EPI epi)
{
    const int tid = threadIdx.x;
    const int lane = tid & 63, w = tid >> 6;
    const int wr = w >> 1, wc = w & 1;
    const int lr = lane & 15, lg = lane >> 4;

    const int srow = tid >> 3;
    const int cswz = (tid & 7) ^ (srow & 7);
    const unsigned short* gA0 = Ap + (size_t)(m0 + srow) * 1024 + cswz * 8;
    const unsigned short* gB0 = Bp + (size_t)(n0 + srow) * 1024 + cswz * 8;
    unsigned short* dA = sA + tid * 8;
    unsigned short* dB = sB + tid * 8;

    const int sw0 = ((0 + lg) ^ (lr & 7)) * 8;
    const int sw1 = ((4 + lg) ^ (lr & 7)) * 8;

    f32x4 acc[4][4];
#pragma unroll
    for (int i = 0; i < 4; ++i)
#pragma unroll
        for (int j = 0; j < 4; ++j)
#pragma unroll
            for (int e = 0; e < 4; ++e) acc[i][j][e] = 0.0f;

#define STG8(T)                                                               \
    {                                                                         \
        const int ko = (T) * 64;                                              \
        _Pragma("unroll")                                                     \
        for (int j = 0; j < 4; ++j) {                                         \
            gload_lds16(gA0 + ko + (size_t)j * 32768, dA + j * 2048);         \
            gload_lds16(gB0 + ko + (size_t)j * 32768, dB + j * 2048);         \
        }                                                                     \
    }

    STG8(0);
    for (int t = 0; t < 16; ++t) {
        asm volatile("s_waitcnt vmcnt(0)" ::: "memory");
        __builtin_amdgcn_s_barrier();

        short8 af[4], bf[4];
#pragma unroll
        for (int mt = 0; mt < 4; ++mt)
            af[mt] = *(const short8*)&sA[(wr * 64 + mt * 16 + lr) * 64 + sw0];
#pragma unroll
        for (int nt = 0; nt < 4; ++nt)
            bf[nt] = *(const short8*)&sB[(wc * 64 + nt * 16 + lr) * 64 + sw0];
        __builtin_amdgcn_s_setprio(1);
#pragma unroll
        for (int mt = 0; mt < 4; ++mt)
#pragma unroll
            for (int nt = 0; nt < 4; ++nt)
                acc[mt][nt] = __builtin_amdgcn_mfma_f32_16x16x32_bf16(
                    af[mt], bf[nt], acc[mt][nt], 0, 0, 0);
        __builtin_amdgcn_s_setprio(0);

#pragma unroll
        for (int mt = 0; mt < 4; ++mt)
            af[mt] = *(const short8*)&sA[(wr * 64 + mt * 16 + lr) * 64 + sw1];
#pragma unroll
        for (int nt = 0; nt < 4; ++nt)
            bf[nt] = *(const short8*)&sB[(wc * 64 + nt * 16 + lr) * 64 + sw1];
        asm volatile("s_waitcnt lgkmcnt(0)" ::: "memory");
        __builtin_amdgcn_s_barrier();
        if (t < 15) STG8(t + 1);
        __builtin_amdgcn_s_setprio(1);
#pragma unroll
        for (int mt = 0; mt < 4; ++mt)
#pragma unroll
            for (int nt = 0; nt < 4; ++nt)
                acc[mt][nt] = __builtin_amdgcn_mfma_f32_16x16x32_bf16(
                    af[mt], bf[nt], acc[mt][nt], 0, 0, 0);
        __builtin_amdgcn_s_setprio(0);
    }
#undef STG8

#pragma unroll
    for (int mt = 0; mt < 4; ++mt)
#pragma unroll
        for (int nt = 0; nt < 4; ++nt) {
            const int col = n0 + wc * 64 + nt * 16 + lr;
#pragma unroll
            for (int i = 0; i < 4; ++i) {
                const int row = m0 + wr * 64 + mt * 16 + lg * 4 + i;
                epi(row, col, acc[mt][nt][i]);
            }
        }
}

// ---- merged projections: Q-proj (1024 tiles) + KV-proj (2048 tiles) ----
__global__ __launch_bounds__(256, 4) void gemm_qkv(
    const unsigned short* __restrict__ QLN, const unsigned short* __restrict__ WQ,
    const unsigned short* __restrict__ CLN, const unsigned short* __restrict__ WKV,
    unsigned short* __restrict__ Qm, unsigned short* __restrict__ KVT,
    const float* __restrict__ q_b, const float* __restrict__ k_b,
    const float* __restrict__ v_b)
{
    __shared__ __attribute__((aligned(16))) unsigned short sA[128 * 64];
    __shared__ __attribute__((aligned(16))) unsigned short sB[128 * 64];

    const int bid = blockIdx.x;                  // 3072 blocks
    const int l = (bid & 7) * 384 + (bid >> 3);  // XCD-chunked

    if (l < 1024) {
        const int m0 = (l >> 3) * 128, n0 = (l & 7) * 128;
        gemm128(sA, sB, QLN, WQ, m0, n0,
            [&](int row, int col, float v) {
                v = elu1(v + q_b[col]);
                Qm[(size_t)row * 1024 + col] = f2bf(v);
            });
    } else {
        const int r = l - 1024;                  // 0..2047
        const int m0 = (r & 15) * 128, n0 = (r >> 4) * 128;
        gemm128(sA, sB, WKV, CLN, m0, n0,
            [&](int row, int col, float v) {
                if (row < 1024) v = elu1(v + k_b[row]);
                else            v = v + v_b[row - 1024];
                KVT[(size_t)row * NROW + col] = f2bf(v);
            });
    }
}

// =====================================================================
// O-projection: round-5 deep-pipelined 256x256/BK=64/8-wave kernel.
// =====================================================================
__global__ __launch_bounds__(512, 2) void gemm_out256(
    const unsigned short* __restrict__ A, const unsigned short* __restrict__ Bm,
    float* __restrict__ Cout, const float* __restrict__ bias,
    const float* __restrict__ resid)
{
    __shared__ __attribute__((aligned(16))) unsigned short smem[65536];
    unsigned short* sAb = smem;           // 2 x 16384
    unsigned short* sBb = smem + 32768;   // 2 x 16384

    const int bid = blockIdx.x;           // 256 blocks
    const int l = (bid & 7) * 32 + (bid >> 3);
    const int m0 = (l >> 2) * 256, n0 = (l & 3) * 256;

    const int tid = threadIdx.x;
    const int lane = tid & 63, w = tid >> 6;
    const int wr = w >> 2, wc = w & 3;          // 2 x 4 wave grid
    const int lr = lane & 15, lg = lane >> 4;

    const int srow = tid >> 3;
    const int cswz = (tid & 7) ^ (srow & 7);
    const unsigned short* gA0 = A  + (size_t)(m0 + srow) * 1024 + cswz * 8;
    const unsigned short* gB0 = Bm + (size_t)(n0 + srow) * 1024 + cswz * 8;

    const int sw0 = ((0 + lg) ^ (lr & 7)) * 8;
    const int sw1 = ((4 + lg) ^ (lr & 7)) * 8;

    f32x4 acc[8][4];
#pragma unroll
    for (int i = 0; i < 8; ++i)
#pragma unroll
        for (int j = 0; j < 4; ++j)
#pragma unroll
            for (int e = 0; e < 4; ++e) acc[i][j][e] = 0.0f;

#define STG(GP, SP, T)                                                        \
    {                                                                         \
        const unsigned short* g = (GP) + (T) * 64;                            \
        unsigned short* d = (SP) + ((T) & 1) * 16384 + tid * 8;               \
        _Pragma("unroll")                                                     \
        for (int L = 0; L < 4; ++L)                                           \
            gload_lds16(g + (size_t)L * 65536, d + L * 4096);                 \
    }

    STG(gB0, sBb, 0); STG(gA0, sAb, 0); STG(gB0, sBb, 1); STG(gA0, sAb, 1);
    asm volatile("s_waitcnt vmcnt(8)" ::: "memory");
    __builtin_amdgcn_s_barrier();

    short8 bvl[2][2];
#pragma unroll
    for (int nt = 0; nt < 2; ++nt) {
        const int rb = (wc * 64 + nt * 16 + lr) * 64;
        bvl[nt][0] = *(const short8*)&sBb[rb + sw0];
        bvl[nt][1] = *(const short8*)&sBb[rb + sw1];
    }

    for (int t = 0; t < 16; ++t) {
        const unsigned short* bA = sAb + (t & 1) * 16384;
        const unsigned short* bB = sBb + (t & 1) * 16384;
        const unsigned short* bBn = sBb + ((t + 1) & 1) * 16384;
        short8 afl[4][2], afh[4][2], bvh[2][2], bvln[2][2];

        // ---- P0 ----
#pragma unroll
        for (int mt = 0; mt < 4; ++mt) {
            const int ra = (wr * 128 + mt * 16 + lr) * 64;
            afl[mt][0] = *(const short8*)&bA[ra + sw0];
            afl[mt][1] = *(const short8*)&bA[ra + sw1];
        }
#pragma unroll
        for (int mt = 0; mt < 4; ++mt) {
            const int ra = (wr * 128 + (mt + 4) * 16 + lr) * 64;
            afh[mt][0] = *(const short8*)&bA[ra + sw0];
            afh[mt][1] = *(const short8*)&bA[ra + sw1];
        }
        asm volatile("s_waitcnt lgkmcnt(8)" ::: "memory");
        __builtin_amdgcn_s_setprio(1);
#pragma unroll
        for (int kk = 0; kk < 2; ++kk)
#pragma unroll
            for (int mt = 0; mt < 4; ++mt)
#pragma unroll
                for (int nt = 0; nt < 2; ++nt)
                    acc[mt][nt] = __builtin_amdgcn_mfma_f32_16x16x32_bf16(
                        afl[mt][kk], bvl[nt][kk], acc[mt][nt], 0, 0, 0);
        __builtin_amdgcn_s_setprio(0);
        __builtin_amdgcn_s_barrier();

        // ---- P1 ----
#pragma unroll
        for (int nt = 0; nt < 2; ++nt) {
            const int rb = (wc * 64 + (nt + 2) * 16 + lr) * 64;
            bvh[nt][0] = *(const short8*)&bB[rb + sw0];
            bvh[nt][1] = *(const short8*)&bB[rb + sw1];
        }
        asm volatile("s_waitcnt lgkmcnt(4)" ::: "memory");
        __builtin_amdgcn_s_setprio(1);
#pragma unroll
        for (int kk = 0; kk < 2; ++kk)
#pragma unroll
            for (int mt = 0; mt < 4; ++mt)
#pragma unroll
                for (int nt = 0; nt < 2; ++nt)
                    acc[mt + 4][nt] = __builtin_amdgcn_mfma_f32_16x16x32_bf16(
                        afh[mt][kk], bvl[nt][kk], acc[mt + 4][nt], 0, 0, 0);
        __builtin_amdgcn_s_setprio(0);
        asm volatile("s_waitcnt vmcnt(0)" ::: "memory");
        __builtin_amdgcn_s_barrier();

        // ---- P2 ----
        if (t < 15) {
#pragma unroll
            for (int nt = 0; nt < 2; ++nt) {
                const int rb = (wc * 64 + nt * 16 + lr) * 64;
                bvln[nt][0] = *(const short8*)&bBn[rb + sw0];
                bvln[nt][1] = *(const short8*)&bBn[rb + sw1];
            }
        }
        if (t + 2 < 16) STG(gA0, sAb, t + 2);
        if (t < 15) asm volatile("s_waitcnt lgkmcnt(4)" ::: "memory");
        else        asm volatile("s_waitcnt lgkmcnt(0)" ::: "memory");
        __builtin_amdgcn_s_setprio(1);
#pragma unroll
        for (int kk = 0; kk < 2; ++kk)
#pragma unroll
            for (int mt = 0; mt < 4; ++mt)
#pragma unroll
                for (int nt = 0; nt < 2; ++nt)
                    acc[mt + 4][nt + 2] = __builtin_amdgcn_mfma_f32_16x16x32_bf16(
                        afh[mt][kk], bvh[nt][kk], acc[mt + 4][nt + 2], 0, 0, 0);
        __builtin_amdgcn_s_setprio(0);
        __builtin_amdgcn_s_barrier();

        // ---- P3 ----
        if (t + 2 < 16) STG(gB0, sBb, t + 2);
        __builtin_amdgcn_s_setprio(1);
#pragma unroll
        for (int kk = 0; kk < 2; ++kk)
#pragma unroll
            for (int mt = 0; mt < 4; ++mt)
#pragma unroll
                for (int nt = 0; nt < 2; ++nt)
                    acc[mt][nt + 2] = __builtin_amdgcn_mfma_f32_16x16x32_bf16(
                        afl[mt][kk], bvh[nt][kk], acc[mt][nt + 2], 0, 0, 0);
        __builtin_amdgcn_s_setprio(0);

        if (t < 15) {
#pragma unroll
            for (int nt = 0; nt < 2; ++nt) {
                bvl[nt][0] = bvln[nt][0];
                bvl[nt][1] = bvln[nt][1];
            }
        }
    }
#undef STG

#pragma unroll
    for (int mt = 0; mt < 8; ++mt) {
#pragma unroll
        for (int nt = 0; nt < 4; ++nt) {
            const int col = n0 + wc * 64 + nt * 16 + lr;
#pragma unroll
            for (int i = 0; i < 4; ++i) {
                const int row = m0 + wr * 128 + mt * 16 + lg * 4 + i;
                Cout[(size_t)row * 1024 + col] =
                    acc[mt][nt][i] + bias[col] + resid[(size_t)row * 1024 + col];
            }
        }
    }
}

// =====================================================================
// KV partials + Ksum partials; quadrant-per-wave (NO cross-wave reduce,
// no big LDS), 16 n-splits (1024 blocks).
// Wave w owns output quadrant (e: (w>>1)*32, d: (w&1)*32); loops the
// whole 256-col n-chunk. Waves 0,1 also accumulate Ksum for their d-half.
// =====================================================================
__global__ __launch_bounds__(256) void kv_kernel(
    const unsigned short* __restrict__ VT, const unsigned short* __restrict__ KT,
    float* __restrict__ KVTp, float* __restrict__ Ksump)
{
    const int bh = blockIdx.x, sp = blockIdx.y;   // 64 x 16
    const int b = bh >> 4, h = bh & 15;
    const int tid = threadIdx.x, lane = tid & 63, w = tid >> 6;
    const int lr = lane & 15, lg = lane >> 4;
    const int eh = (w >> 1) * 32, dh = (w & 1) * 32;

    f32x4 acc[2][2];
#pragma unroll
    for (int i = 0; i < 2; ++i)
#pragma unroll
        for (int j = 0; j < 2; ++j)
#pragma unroll
            for (int e = 0; e < 4; ++e) acc[i][j][e] = 0.0f;
    float kp[2] = {0.0f, 0.0f};

    const size_t colbase = (size_t)b * 4096 + sp * 256 + lg * 8;
    const unsigned short* va = VT + (size_t)(h * 64 + eh + lr) * NROW + colbase;
    const unsigned short* ka = KT + (size_t)(h * 64 + dh + lr) * NROW + colbase;

    for (int ks = 0; ks < 8; ++ks) {              // 8 x 32 n = 256 n
        short8 af[2], bfv[2];
        af[0]  = *(const short8*)(va + ks * 32);
        af[1]  = *(const short8*)(va + (size_t)16 * NROW + ks * 32);
        bfv[0] = *(const short8*)(ka + ks * 32);
        bfv[1] = *(const short8*)(ka + (size_t)16 * NROW + ks * 32);
#pragma unroll
        for (int mt = 0; mt < 2; ++mt)
#pragma unroll
            for (int nt = 0; nt < 2; ++nt)
                acc[mt][nt] = __builtin_amdgcn_mfma_f32_16x16x32_bf16(
                    af[mt], bfv[nt], acc[mt][nt], 0, 0, 0);
        if (w < 2) {
#pragma unroll
            for (int nt = 0; nt < 2; ++nt)
#pragma unroll
                for (int j = 0; j < 8; ++j)
                    kp[nt] += bf2f((unsigned short)bfv[nt][j]);
        }
    }

    // outputs: quadrant (e = eh + mt*16 + lg*4 + i, d = dh + nt*16 + lr)
    float* out = KVTp + ((size_t)sp * 64 + bh) * 4096;
#pragma unroll
    for (int mt = 0; mt < 2; ++mt)
#pragma unroll
        for (int nt = 0; nt < 2; ++nt)
#pragma unroll
            for (int i = 0; i < 4; ++i)
                out[(eh + mt * 16 + lg * 4 + i) * 64 + dh + nt * 16 + lr] =
                    acc[mt][nt][i];

    if (w < 2) {
#pragma unroll
        for (int nt = 0; nt < 2; ++nt) {
            kp[nt] += __shfl_xor(kp[nt], 16);
            kp[nt] += __shfl_xor(kp[nt], 32);
        }
        if (lane < 16) {
#pragma unroll
            for (int nt = 0; nt < 2; ++nt)
                Ksump[((size_t)sp * 64 + bh) * 64 + dh + nt * 16 + lane] = kp[nt];
        }
    }
}

// =====================================================================
// Reduce the 16 split-partials once: KVs[bh][4096], Ks[bh][64].
// =====================================================================
__global__ __launch_bounds__(256) void kvred_kernel(
    const float* __restrict__ KVTp, const float* __restrict__ Ksump,
    float* __restrict__ KVs, float* __restrict__ Ks)
{
    const int bh = blockIdx.x;
    const int tid = threadIdx.x;
    for (int i = tid * 4; i < 4096; i += 1024) {
        f32x4 s = {0.0f, 0.0f, 0.0f, 0.0f};
#pragma unroll
        for (int sp = 0; sp < 16; ++sp) {
            f32x4 v = *(const f32x4*)(KVTp + ((size_t)sp * 64 + bh) * 4096 + i);
            s[0] += v[0]; s[1] += v[1]; s[2] += v[2]; s[3] += v[3];
        }
        *(f32x4*)(KVs + (size_t)bh * 4096 + i) = s;
    }
    if (tid < 64) {
        float s = 0.0f;
#pragma unroll
        for (int sp = 0; sp < 16; ++sp)
            s += Ksump[((size_t)sp * 64 + bh) * 64 + tid];
        Ks[bh * 64 + tid] = s;
    }
}

// =====================================================================
// A2[n][h*64+e] = (sum_d Q[n][h*64+d] * KV[d][e]) * invZ(n,h); z fused.
// =====================================================================
__global__ __launch_bounds__(256) void a2_kernel(
    const unsigned short* __restrict__ Q, const float* __restrict__ KVs,
    const float* __restrict__ Ks, unsigned short* __restrict__ A2)
{
    const int m0 = blockIdx.x * 128, h = blockIdx.y;
    const int b = m0 >> 12, bh = (b << 4) + h;
    const int tid = threadIdx.x, lane = tid & 63, w = tid >> 6;
    const int wr = w >> 1, wc = w & 1;
    const int lr = lane & 15, lg = lane >> 4;

    __shared__ float ksum_s[64];
    if (tid < 64) ksum_s[tid] = Ks[bh * 64 + tid];
    __syncthreads();

    f32x4 acc[4][2];
#pragma unroll
    for (int i = 0; i < 4; ++i)
#pragma unroll
        for (int j = 0; j < 2; ++j)
#pragma unroll
            for (int e = 0; e < 4; ++e) acc[i][j][e] = 0.0f;
    float zp[4] = {0.0f, 0.0f, 0.0f, 0.0f};

    const unsigned short* qa = Q + (size_t)(m0 + wr * 64 + lr) * DDIM + h * 64 + lg * 8;
    const float* kvb = KVs + (size_t)bh * 4096 + (wc * 32 + lr) * 64 + lg * 8;

#pragma unroll
    for (int ks = 0; ks < 2; ++ks) {
        short8 af[4];
#pragma unroll
        for (int mt = 0; mt < 4; ++mt)
            af[mt] = *(const short8*)(qa + (size_t)mt * 16 * DDIM + ks * 32);
#pragma unroll
        for (int mt = 0; mt < 4; ++mt)
#pragma unroll
            for (int j = 0; j < 8; ++j)
                zp[mt] += bf2f((unsigned short)af[mt][j]) * ksum_s[ks * 32 + lg * 8 + j];
        short8 bfv[2];
#pragma unroll
        for (int nt = 0; nt < 2; ++nt) {
            const float* p = kvb + nt * 16 * 64 + ks * 32;
            f32x4 v0 = *(const f32x4*)(p);
            f32x4 v1 = *(const f32x4*)(p + 4);
            short8 t;
#pragma unroll
            for (int j = 0; j < 4; ++j) {
                t[j]     = (short)f2bf(v0[j]);
                t[j + 4] = (short)f2bf(v1[j]);
            }
            bfv[nt] = t;
        }
#pragma unroll
        for (int mt = 0; mt < 4; ++mt)
#pragma unroll
            for (int nt = 0; nt < 2; ++nt)
                acc[mt][nt] = __builtin_amdgcn_mfma_f32_16x16x32_bf16(
                    af[mt], bfv[nt], acc[mt][nt], 0, 0, 0);
    }

    float zinv[4];
#pragma unroll
    for (int mt = 0; mt < 4; ++mt) {
        zp[mt] += __shfl_xor(zp[mt], 16);
        zp[mt] += __shfl_xor(zp[mt], 32);
        zinv[mt] = 1.0f / fmaxf(zp[mt], 1e-6f);
    }

#pragma unroll
    for (int mt = 0; mt < 4; ++mt)
#pragma unroll
        for (int nt = 0; nt < 2; ++nt)
#pragma unroll
            for (int i = 0; i < 4; ++i) {
                const int row = m0 + wr * 64 + mt * 16 + lg * 4 + i;
                const int col = h * 64 + wc * 32 + nt * 16 + lr;
                const float zi = __shfl(zinv[mt], lg * 4 + i);
                const float v = acc[mt][nt][i] * zi;
                A2[(size_t)row * DDIM + col] = f2bf(v);
            }
}

// =====================================================================
// host
// =====================================================================
extern "C" void kernel_launch(void* const* d_in, const int* in_sizes, int n_in,
                              void* d_out, int out_size, void* d_ws, size_t ws_size,
                              hipStream_t stream)
{
    const float* query   = (const float*)d_in[0];
    const float* context = (const float*)d_in[1];
    const float* q_w = (const float*)d_in[2];
    const float* q_b = (const float*)d_in[3];
    const float* k_w = (const float*)d_in[4];
    const float* k_b = (const float*)d_in[5];
    const float* v_w = (const float*)d_in[6];
    const float* v_b = (const float*)d_in[7];
    const float* o_w = (const float*)d_in[8];
    const float* o_b = (const float*)d_in[9];
    const float* lnq_g = (const float*)d_in[10];
    const float* lnq_b = (const float*)d_in[11];
    const float* lnk_g = (const float*)d_in[12];
    const float* lnk_b = (const float*)d_in[13];

    char* ws = (char*)d_ws;
    unsigned short* WQ  = (unsigned short*)(ws);                    // 0..2 MiB
    unsigned short* WKV = (unsigned short*)(ws + (2u << 20));       // 2..6
    unsigned short* WO  = (unsigned short*)(ws + (6u << 20));       // 6..8
    unsigned short* QLN = (unsigned short*)(ws + (8u << 20));       // 8..40
    unsigned short* CLN = (unsigned short*)(ws + (40u << 20));      // 40..72 (dead after qkv)
    unsigned short* Qm  = (unsigned short*)(ws + (72u << 20));      // 72..104
    unsigned short* KT  = (unsigned short*)(ws + (104u << 20));     // KVT rows 0-1023
    unsigned short* VT  = (unsigned short*)(ws + (136u << 20));     // KVT rows 1024-2047
    // attention-core scratch reuses the dead CLN region:
    float* KVTp  = (float*)(ws + (40u << 20));                      // 16 MiB (16 splits)
    float* Ksump = (float*)(ws + (56u << 20));                      // 256 KiB
    float* KVs   = (float*)(ws + (57u << 20));                      // 1 MiB
    float* Ks    = (float*)(ws + (58u << 20));                      // 16 KiB
    unsigned short* A2 = QLN;                                       // alias (QLN dead)

    ln_kernel<<<8192 + 4096, 256, 0, stream>>>(
        query, context, lnq_g, lnq_b, lnk_g, lnk_b, QLN, CLN,
        q_w, k_w, v_w, o_w, WQ);
    gemm_qkv<<<3072, 256, 0, stream>>>(QLN, WQ, CLN, WKV, Qm, KT,
                                       q_b, k_b, v_b);
    kv_kernel<<<dim3(64, 16), 256, 0, stream>>>(VT, KT, KVTp, Ksump);
    kvred_kernel<<<64, 256, 0, stream>>>(KVTp, Ksump, KVs, Ks);
    a2_kernel<<<dim3(128, 16), 256, 0, stream>>>(Qm, KVs, Ks, A2);
    gemm_out256<<<256, 512, 0, stream>>>(A2, WO, (float*)d_out, o_b, query);
}